// Round 12
// baseline (578.060 us; speedup 1.0000x reference)
//
#include <hip/hip_runtime.h>

#define XS 264           // X LDS row stride in bf16 elems (528 B; A b128 reads at 2-way floor)
#define CHUNK_ELEMS 8192 // one 32k x 256n weight chunk, layout [quad][n][8]

typedef __bf16 bf16x8 __attribute__((ext_vector_type(8)));
typedef float f32x4 __attribute__((ext_vector_type(4)));

__device__ __forceinline__ unsigned short f2bf(float f) {
    unsigned int u = __float_as_uint(f);
    u += 0x7fffu + ((u >> 16) & 1u);
    return (unsigned short)(u >> 16);
}

// Weight image (bf16 elem offsets). Layers 0..3 stored as swizzled chunk
// images: chunk c covers k in [c*32,c*32+32); element (quad,n,j) at offset
// ((quad*256+n)*8+j) holds W[n][c*32+quad*8+j]. 16 consecutive lanes read
// 256 contiguous bytes -> fully coalesced global B-frag loads.
#define OFF0 0        // L0: 5 chunks (K padded 132->160, cols permuted [f1|f2|rel,cell|0])
#define OFF1 40960    // L1: 8 chunks
#define OFF2 106496   // L2
#define OFF3 172032   // L3
#define OFF4 237568   // w4p: 16 x 256 plain (rows 3..15 zero)
#define WTOT 241664
#define NHWC_ELEMS (4 * 4096 * 64)

__global__ void prep_weights(const float* __restrict__ w0, const float* __restrict__ w1,
                             const float* __restrict__ w2, const float* __restrict__ w3,
                             const float* __restrict__ w4, unsigned short* __restrict__ wsp) {
    int idx = blockIdx.x * 256 + threadIdx.x;
    if (idx >= WTOT) return;
    unsigned short v = 0;
    if (idx < OFF4) {
        int l, base;
        if (idx < OFF1)      { l = 0; base = OFF0; }
        else if (idx < OFF2) { l = 1; base = OFF1; }
        else if (idx < OFF3) { l = 2; base = OFF2; }
        else                 { l = 3; base = OFF3; }
        int j = idx - base;
        int c = j >> 13;
        int u = j & 8191;
        int flat16 = u >> 3, jj = u & 7;
        int quad = flat16 >> 8, n = flat16 & 255;
        int k = c * 32 + quad * 8 + jj;
        if (l == 0) {
            if (k < 64)       v = f2bf(w0[n * 132 + k]);
            else if (k < 128) v = f2bf(w0[n * 132 + 68 + (k - 64)]);
            else if (k < 132) v = f2bf(w0[n * 132 + 64 + (k - 128)]);
        } else {
            const float* w = (l == 1) ? w1 : (l == 2) ? w2 : w3;
            v = f2bf(w[n * 256 + k]);
        }
    } else {
        int j = idx - OFF4;
        if ((j >> 8) < 3) v = f2bf(w4[j]);
    }
    wsp[idx] = v;
}

__global__ void transpose_nhwc(const float* __restrict__ inp1, const float* __restrict__ inp2,
                               unsigned short* __restrict__ t1, unsigned short* __restrict__ t2) {
    int idx = blockIdx.x * 256 + threadIdx.x;
    int tensor = idx >> 14;
    int pos = idx & 16383;
    const float* src = tensor ? inp2 : inp1;
    unsigned short* dst = tensor ? t2 : t1;
    int b = pos >> 12, flat = pos & 4095;
    const float* s = src + (size_t)b * 64 * 4096 + flat;
    unsigned short* d = dst + (size_t)pos * 64;
#pragma unroll
    for (int c = 0; c < 64; ++c) d[c] = f2bf(s[c * 4096]);
}

__global__ __launch_bounds__(512, 4)
void liif_mlp(const unsigned short* __restrict__ t1, const unsigned short* __restrict__ t2,
              const float* __restrict__ coord, const float* __restrict__ cell,
              const float* __restrict__ b0, const float* __restrict__ b1,
              const float* __restrict__ b2, const float* __restrict__ b3,
              const float* __restrict__ b4,
              const unsigned short* __restrict__ wsp,
              float* __restrict__ out) {
    __shared__ unsigned short Xs[128 * XS];          // 67,584 B — activations only
    __shared__ float areaS[128];

    const int t = threadIdx.x;
    const int lane = t & 63;
    const int wv = t >> 6;            // 0..7

    // ---------------- gather: X [128 rows x 160 cols], 4 threads per row ----------------
    {
        int lr = t >> 2, sub = t & 3;
        int rg = blockIdx.x * 128 + lr;
        int p = rg >> 2, e = rg & 3;
        int b = p >> 16;
        float c0r = coord[(size_t)p * 2 + 0];
        float c1r = coord[(size_t)p * 2 + 1];
        float vx = (e & 2) ? 1.0f : -1.0f;
        float vy = (e & 1) ? 1.0f : -1.0f;
        const float lo = -1.0f + 1e-6f, hi = 1.0f - 1e-6f;
        float c0 = fminf(fmaxf(c0r + vx * (1.0f / 64.0f) + 1e-6f, lo), hi);
        float c1 = fminf(fmaxf(c1r + vy * (1.0f / 64.0f) + 1e-6f, lo), hi);
        int ih = (int)rintf((c0 + 1.0f) * 32.0f - 0.5f);
        ih = min(63, max(0, ih));
        int iw = (int)rintf((c1 + 1.0f) * 32.0f - 0.5f);
        iw = min(63, max(0, iw));
        int flat = ih * 64 + iw;
        size_t pos = (size_t)b * 4096 + flat;
        const uint4* g1 = (const uint4*)(t1 + pos * 64 + sub * 16);
        const uint4* g2 = (const uint4*)(t2 + pos * 64 + sub * 16);
        uint4 a0 = g1[0], a1 = g1[1];
        uint4 c0v = g2[0], c1v = g2[1];
        uint4* d1 = (uint4*)&Xs[lr * XS + sub * 16];
        uint4* d2 = (uint4*)&Xs[lr * XS + 64 + sub * 16];
        d1[0] = a0; d1[1] = a1;
        d2[0] = c0v; d2[1] = c1v;
        if (sub == 0) {
            float qc0 = -1.0f + (2.0f * ih + 1.0f) * (1.0f / 64.0f);
            float qc1 = -1.0f + (2.0f * iw + 1.0f) * (1.0f / 64.0f);
            float rel0 = (c0r - qc0) * 64.0f;
            float rel1 = (c1r - qc1) * 64.0f;
            Xs[lr * XS + 128] = f2bf(rel0);
            Xs[lr * XS + 129] = f2bf(rel1);
            Xs[lr * XS + 130] = f2bf(cell[(size_t)p * 2 + 0] * 64.0f);
            Xs[lr * XS + 131] = f2bf(cell[(size_t)p * 2 + 1] * 64.0f);
#pragma unroll
            for (int c = 132; c < 160; ++c) Xs[lr * XS + c] = 0;
            areaS[lr] = fabsf(rel0 * rel1) + 1e-9f;
        }
    }
    __syncthreads();

    const int ln15 = lane & 15;
    const int quad = lane >> 4;
    const int mw = wv >> 2;          // row half: rows mw*64 .. +63
    const int nw = wv & 3;           // col group: cols nw*64 .. +63
    const int cb = nw * 64;
    const int rbase = mw * 64;

    const unsigned short* wlbase[4] = {wsp + OFF0, wsp + OFF1, wsp + OFF2, wsp + OFF3};
    const float* bptr[4] = {b0, b1, b2, b3};

#pragma unroll
    for (int l = 0; l < 4; ++l) {
        const int nk = (l == 0) ? 5 : 8;
        f32x4 acc[4][4];
#pragma unroll
        for (int mt = 0; mt < 4; ++mt)
#pragma unroll
            for (int nt = 0; nt < 4; ++nt)
                acc[mt][nt] = (f32x4){0.f, 0.f, 0.f, 0.f};

        // per-lane weight base inside a chunk (coalesced: 16 lanes -> 256 B)
        const unsigned short* bp = wlbase[l] + ((size_t)quad * 256 + cb + ln15) * 8;

#pragma unroll
        for (int i = 0; i < nk; ++i) {
            bf16x8 bfr[4], af[4];
#pragma unroll
            for (int nt = 0; nt < 4; ++nt)
                bfr[nt] = *(const bf16x8*)(bp + (size_t)i * CHUNK_ELEMS + nt * 128);
#pragma unroll
            for (int mt = 0; mt < 4; ++mt)
                af[mt] = *(const bf16x8*)&Xs[(rbase + mt * 16 + ln15) * XS + i * 32 + quad * 8];
            // swapped operands: D = W·X^T -> lane: "col"(=ln15)=x_row, "row"(=quad*4+reg)=w_n
#pragma unroll
            for (int mt = 0; mt < 4; ++mt)
#pragma unroll
                for (int nt = 0; nt < 4; ++nt)
                    acc[mt][nt] = __builtin_amdgcn_mfma_f32_16x16x32_bf16(
                        bfr[nt], af[mt], acc[mt][nt], 0, 0, 0);
        }
        __syncthreads();             // all Xs k-input reads for this layer done

        // bias loaded here (off the k-loop critical path)
        const float* bl = bptr[l];
#pragma unroll
        for (int mt = 0; mt < 4; ++mt) {
            int row = rbase + mt * 16 + ln15;
#pragma unroll
            for (int nt = 0; nt < 4; ++nt) {
                f32x4 bv = *(const f32x4*)(bl + cb + nt * 16 + quad * 4);
                int col = cb + nt * 16 + quad * 4;
                ushort4 pv;
                pv.x = f2bf(fmaxf(acc[mt][nt][0] + bv[0], 0.0f));
                pv.y = f2bf(fmaxf(acc[mt][nt][1] + bv[1], 0.0f));
                pv.z = f2bf(fmaxf(acc[mt][nt][2] + bv[2], 0.0f));
                pv.w = f2bf(fmaxf(acc[mt][nt][3] + bv[3], 0.0f));
                *(ushort4*)&Xs[row * XS + col] = pv;   // 8 B vector write
            }
        }
        __syncthreads();             // activations visible to all waves
    }

    // ---------------- layer 4: [128 x 256] @ [256 x 16], wave wv owns rows wv*16..+15 ----------------
    {
        f32x4 acc4 = (f32x4){0.f, 0.f, 0.f, 0.f};
        const unsigned short* W4 = wsp + OFF4;
#pragma unroll
        for (int k0 = 0; k0 < 256; k0 += 32) {
            bf16x8 a = *(const bf16x8*)&Xs[(wv * 16 + ln15) * XS + k0 + quad * 8];
            bf16x8 bb = *(const bf16x8*)(W4 + ln15 * 256 + k0 + quad * 8);
            acc4 = __builtin_amdgcn_mfma_f32_16x16x32_bf16(a, bb, acc4, 0, 0, 0);
        }
        int plocal = wv * 4 + quad;          // point within block (0..31), reg r = branch e
        float a0 = areaS[plocal * 4 + 0];
        float a1 = areaS[plocal * 4 + 1];
        float a2 = areaS[plocal * 4 + 2];
        float a3 = areaS[plocal * 4 + 3];
        float tot = a0 + a1 + a2 + a3;
        float r = (acc4[0] * a3 + acc4[1] * a2 + acc4[2] * a1 + acc4[3] * a0) / tot;
        if (ln15 < 3) {
            size_t pg = (size_t)blockIdx.x * 32 + plocal;
            out[pg * 3 + ln15] = r + b4[ln15];
        }
    }
}

extern "C" void kernel_launch(void* const* d_in, const int* in_sizes, int n_in,
                              void* d_out, int out_size, void* d_ws, size_t ws_size,
                              hipStream_t stream) {
    const float* inp1  = (const float*)d_in[0];
    const float* inp2  = (const float*)d_in[1];
    const float* coord = (const float*)d_in[2];
    const float* cell  = (const float*)d_in[3];
    const float* w0 = (const float*)d_in[4];
    const float* b0 = (const float*)d_in[5];
    const float* w1 = (const float*)d_in[6];
    const float* b1 = (const float*)d_in[7];
    const float* w2 = (const float*)d_in[8];
    const float* b2 = (const float*)d_in[9];
    const float* w3 = (const float*)d_in[10];
    const float* b3 = (const float*)d_in[11];
    const float* w4 = (const float*)d_in[12];
    const float* b4 = (const float*)d_in[13];
    float* out = (float*)d_out;

    unsigned short* wsp = (unsigned short*)d_ws;
    unsigned short* t1 = wsp + WTOT;
    unsigned short* t2 = t1 + NHWC_ELEMS;

    prep_weights<<<(WTOT + 255) / 256, 256, 0, stream>>>(w0, w1, w2, w3, w4, wsp);
    transpose_nhwc<<<32768 / 256, 256, 0, stream>>>(inp1, inp2, t1, t2);
    liif_mlp<<<8192, 512, 0, stream>>>(t1, t2, coord, cell,
                                       b0, b1, b2, b3, b4, wsp, out);
}